// Round 1
// baseline (19339.255 us; speedup 1.0000x reference)
//
#include <hip/hip_runtime.h>
#include <stdint.h>

#define S_LEN 2048
#define NW 16          // workgroups per batch-group
#define KPAD 584       // 576 + 8 bf16 pad (16B-aligned rows, 2-way-max LDS banks)

typedef __attribute__((ext_vector_type(8))) short short8;
typedef __attribute__((ext_vector_type(4))) float f32x4;

__device__ __forceinline__ unsigned short f2bf(float f) {
  union { float f; unsigned int u; } v; v.f = f;
  unsigned int u = v.u;
  u = (u + 0x7FFFu + ((u >> 16) & 1u)) >> 16;   // round-to-nearest-even
  return (unsigned short)u;
}

__device__ __forceinline__ float sigm(float x) { return 1.f / (1.f + __expf(-x)); }
__device__ __forceinline__ float tanh_f(float x) {
  float e = __expf(2.f * x);
  return 1.f - 2.f / (e + 1.f);
}

// Device-scope barrier among NW workgroups of one batch-group.
// One fresh counter slot per use (zeroed by hipMemsetAsync each launch).
__device__ __forceinline__ void group_barrier(unsigned int* p, unsigned int target) {
  __syncthreads();                      // drains each wave's vmcnt -> stores in L2
  if (threadIdx.x == 0) {
    __threadfence();                    // agent release: L2 writeback
    __hip_atomic_fetch_add(p, 1u, __ATOMIC_RELEASE, __HIP_MEMORY_SCOPE_AGENT);
    unsigned int it = 0;
    while (__hip_atomic_load(p, __ATOMIC_RELAXED, __HIP_MEMORY_SCOPE_AGENT) < target) {
      __builtin_amdgcn_s_sleep(1);
      if (++it > (1u << 22)) break;     // safety: never hang the harness
    }
    __threadfence();                    // agent acquire: invalidate L1/L2
  }
  __syncthreads();
}

// ---- prep: cast/reorder weights to bf16 in workspace --------------------
// WgT [1536][576]: rows 0..511 = Wz, 512..1023 = Wr, 1024..1535 = Wh with
// K reordered to [x(64); rh(512)] so all gates share the unified K-order
// u = [x ; h].  W1T [512][512], W2T [64][512]: row-major = per-output-col K.
__global__ void prep_kernel(const float* __restrict__ Wz, const float* __restrict__ Wr,
                            const float* __restrict__ Wh, const float* __restrict__ W1,
                            const float* __restrict__ W2,
                            unsigned short* __restrict__ WgT,
                            unsigned short* __restrict__ W1T,
                            unsigned short* __restrict__ W2T) {
  const int total = 1536 * 576 + 512 * 512 + 64 * 512;
  for (int idx = blockIdx.x * 256 + threadIdx.x; idx < total; idx += gridDim.x * 256) {
    if (idx < 1536 * 576) {
      int row = idx / 576, k = idx % 576;
      float v;
      if (row < 512)       v = Wz[row * 576 + k];
      else if (row < 1024) v = Wr[(row - 512) * 576 + k];
      else {
        int r = row - 1024;
        v = (k < 64) ? Wh[r * 576 + 512 + k] : Wh[r * 576 + (k - 64)];
      }
      WgT[idx] = f2bf(v);
    } else if (idx < 1536 * 576 + 512 * 512) {
      int i = idx - 1536 * 576;
      W1T[i] = f2bf(W1[i]);
    } else {
      int i = idx - 1536 * 576 - 512 * 512;
      W2T[i] = f2bf(W2[i]);
    }
  }
}

// ---- recurrence: 32 WGs = 2 batch-groups x 16 column-slice WGs ----------
// WG (g,w): batches g*16..g*16+15, columns w*32..w*32+31 of z/r/hh/h.
// LDS: weight slice [96][KPAD] bf16 (resident), A buffer [16][KPAD] bf16
// (cols 0..63 = x_t, 64..575 = h or r*h), h fp32 state [16][32].
__global__ void __launch_bounds__(256, 1) recur_kernel(
    const float* __restrict__ x, const float* __restrict__ h0,
    const float* __restrict__ bz, const float* __restrict__ br,
    const float* __restrict__ bh, const unsigned short* __restrict__ WgT,
    unsigned short* __restrict__ hbuf, unsigned short* __restrict__ rhbuf,
    unsigned short* __restrict__ h_all, float* __restrict__ h_last,
    unsigned int* __restrict__ ctr) {
  extern __shared__ char smem[];
  unsigned short* Wlds = (unsigned short*)smem;          // [96][KPAD]
  unsigned short* Abuf = Wlds + 96 * KPAD;               // [16][KPAD]
  float* hfp = (float*)(Abuf + 16 * KPAD);               // [16][32]

  const int wg = blockIdx.x;
  const int g = wg >> 4;        // batch group
  const int w = wg & 15;        // column slice
  const int tid = threadIdx.x;
  const int lane = tid & 63;
  const int wave = tid >> 6;
  const int crow = (lane >> 4) << 2;  // C/D row base
  const int ccol = lane & 15;         // C/D col

  // load resident weight slice: local row lr -> gate=lr>>5, col=lr&31
  for (int i = tid; i < 96 * 72; i += 256) {
    int lr = i / 72, c = i % 72;
    int gate = lr >> 5, col = lr & 31;
    const uint4* src = (const uint4*)(WgT + (size_t)(gate * 512 + w * 32 + col) * 576);
    *(uint4*)(Wlds + lr * KPAD + c * 8) = src[c];
  }
  // fp32 h state slice from h0
  for (int i = tid; i < 16 * 32; i += 256) {
    int m = i >> 5, c = i & 31;
    hfp[m * 32 + c] = h0[(size_t)(g * 16 + m) * 512 + w * 32 + c];
  }
  __syncthreads();

  unsigned int* myctr = ctr + g * 4096;
  float zreg[4];

  for (int t = 0; t < S_LEN; ++t) {
    // ---- stage A operand: x_t (bf16) ----
    {
      int i = tid;  // exactly 256 iterations
      int m = i >> 4, c4 = i & 15;
      float4 xv = *(const float4*)(x + ((size_t)(g * 16 + m) * S_LEN + t) * 64 + c4 * 4);
      unsigned short* d = Abuf + m * KPAD + c4 * 4;
      d[0] = f2bf(xv.x); d[1] = f2bf(xv.y); d[2] = f2bf(xv.z); d[3] = f2bf(xv.w);
    }
    // ---- stage A operand: h_{t-1} ----
    if (t == 0) {
      for (int i = tid; i < 16 * 128; i += 256) {
        int m = i >> 7, c4 = i & 127;
        float4 hv = *(const float4*)(h0 + (size_t)(g * 16 + m) * 512 + c4 * 4);
        unsigned short* d = Abuf + m * KPAD + 64 + c4 * 4;
        d[0] = f2bf(hv.x); d[1] = f2bf(hv.y); d[2] = f2bf(hv.z); d[3] = f2bf(hv.w);
      }
    } else {
      for (int i = tid; i < 16 * 64; i += 256) {
        int m = i >> 6, c8 = i & 63;
        uint4 v = *(const uint4*)(hbuf + (size_t)(g * 16 + m) * 512 + c8 * 8);
        *(uint4*)(Abuf + m * KPAD + 64 + c8 * 8) = v;
      }
    }
    __syncthreads();

    // ---- phase A: z on waves 0,1; r on waves 2,3 ----
    {
      const int gsel = wave >> 1;   // 0=z, 1=r
      const int tile = wave & 1;
      const unsigned short* Ap = Abuf + ccol * KPAD + ((lane >> 4) << 3);
      const unsigned short* Bp = Wlds + (gsel * 32 + tile * 16 + ccol) * KPAD + ((lane >> 4) << 3);
      f32x4 acc = {0.f, 0.f, 0.f, 0.f};
#pragma unroll
      for (int kk = 0; kk < 18; ++kk) {
        short8 a = *(const short8*)(Ap + kk * 32);
        short8 b = *(const short8*)(Bp + kk * 32);
        acc = __builtin_amdgcn_mfma_f32_16x16x32_bf16(a, b, acc, 0, 0, 0);
      }
      const int nloc = tile * 16 + ccol;
      const int ng = w * 32 + nloc;
      const float bias = (gsel == 0) ? bz[ng] : br[ng];
      if (gsel == 0) {
#pragma unroll
        for (int j = 0; j < 4; ++j) zreg[j] = sigm(acc[j] + bias);
      } else {
#pragma unroll
        for (int j = 0; j < 4; ++j) {
          int m = crow + j;
          float rv = sigm(acc[j] + bias);
          float rh = rv * hfp[m * 32 + nloc];
          rhbuf[(size_t)(g * 16 + m) * 512 + ng] = f2bf(rh);
        }
      }
    }
    group_barrier(myctr + t * 2, NW);

    // overwrite A h-part with full r*h vector
    for (int i = tid; i < 16 * 64; i += 256) {
      int m = i >> 6, c8 = i & 63;
      uint4 v = *(const uint4*)(rhbuf + (size_t)(g * 16 + m) * 512 + c8 * 8);
      *(uint4*)(Abuf + m * KPAD + 64 + c8 * 8) = v;
    }
    __syncthreads();

    // ---- phase B: h_hat + state update on waves 0,1 ----
    if (wave < 2) {
      const unsigned short* Ap = Abuf + ccol * KPAD + ((lane >> 4) << 3);
      const unsigned short* Bp = Wlds + (64 + wave * 16 + ccol) * KPAD + ((lane >> 4) << 3);
      f32x4 acc = {0.f, 0.f, 0.f, 0.f};
#pragma unroll
      for (int kk = 0; kk < 18; ++kk) {
        short8 a = *(const short8*)(Ap + kk * 32);
        short8 b = *(const short8*)(Bp + kk * 32);
        acc = __builtin_amdgcn_mfma_f32_16x16x32_bf16(a, b, acc, 0, 0, 0);
      }
      const int nloc = wave * 16 + ccol;
      const int ng = w * 32 + nloc;
      const float bias = bh[ng];
#pragma unroll
      for (int j = 0; j < 4; ++j) {
        int m = crow + j;
        float hh = tanh_f(acc[j] + bias);
        float hold = hfp[m * 32 + nloc];
        float z = zreg[j];
        float hn = (1.f - z) * hold + z * hh;
        hfp[m * 32 + nloc] = hn;
        unsigned short hb = f2bf(hn);
        hbuf[(size_t)(g * 16 + m) * 512 + ng] = hb;
        h_all[((size_t)(g * 16 + m) * S_LEN + t) * 512 + ng] = hb;
        if (t == S_LEN - 1) h_last[(size_t)(g * 16 + m) * 512 + ng] = hn;
      }
    }
    group_barrier(myctr + t * 2 + 1, NW);
  }
}

// ---- head: out = relu(h_all @ W1^T + b1) @ W2^T + b2 --------------------
// One block per 64 consecutive (b,t) rows (2048 % 64 == 0 -> single b/block).
__global__ void __launch_bounds__(256, 1) head_kernel(
    const unsigned short* __restrict__ h_all, const unsigned short* __restrict__ W1T,
    const unsigned short* __restrict__ W2T, const float* __restrict__ b1,
    const float* __restrict__ b2, float* __restrict__ out) {
  extern __shared__ char smem[];
  unsigned short* hs = (unsigned short*)smem;   // [64][520]
  unsigned short* act = hs + 64 * 520;          // [64][520]

  const int tid = threadIdx.x, lane = tid & 63, wave = tid >> 6;
  const int crow = (lane >> 4) << 2, ccol = lane & 15;
  const size_t row0 = (size_t)blockIdx.x * 64;

  for (int i = tid; i < 64 * 64; i += 256) {
    int r = i >> 6, c8 = i & 63;
    uint4 v = *(const uint4*)(h_all + (row0 + r) * 512 + c8 * 8);
    *(uint4*)(hs + r * 520 + c8 * 8) = v;
  }
  __syncthreads();

  // GEMM1: per wave 8 N-tiles (128 cols) x 4 M-tiles; B streamed from L2/L3
  f32x4 acc[8][4];
#pragma unroll
  for (int nt = 0; nt < 8; ++nt)
#pragma unroll
    for (int mt = 0; mt < 4; ++mt) acc[nt][mt] = {0.f, 0.f, 0.f, 0.f};

  for (int k = 0; k < 16; ++k) {
    short8 a[4];
#pragma unroll
    for (int mt = 0; mt < 4; ++mt)
      a[mt] = *(const short8*)(hs + (mt * 16 + ccol) * 520 + k * 32 + ((lane >> 4) << 3));
#pragma unroll
    for (int nt = 0; nt < 8; ++nt) {
      int n0 = (wave * 8 + nt) * 16;
      short8 b = *(const short8*)(W1T + (size_t)(n0 + ccol) * 512 + k * 32 + ((lane >> 4) << 3));
#pragma unroll
      for (int mt = 0; mt < 4; ++mt)
        acc[nt][mt] = __builtin_amdgcn_mfma_f32_16x16x32_bf16(a[mt], b, acc[nt][mt], 0, 0, 0);
    }
  }
#pragma unroll
  for (int nt = 0; nt < 8; ++nt) {
    int n = wave * 128 + nt * 16 + ccol;
    float bias = b1[n];
#pragma unroll
    for (int mt = 0; mt < 4; ++mt)
#pragma unroll
      for (int j = 0; j < 4; ++j) {
        float v = fmaxf(acc[nt][mt][j] + bias, 0.f);
        act[(mt * 16 + crow + j) * 520 + n] = f2bf(v);
      }
  }
  __syncthreads();
  // stage W2T into hs (GEMM1 done reading it)
  for (int i = tid; i < 64 * 64; i += 256) {
    int r = i >> 6, c8 = i & 63;
    uint4 v = *(const uint4*)(W2T + (size_t)r * 512 + c8 * 8);
    *(uint4*)(hs + r * 520 + c8 * 8) = v;
  }
  __syncthreads();

  // GEMM2: per wave 1 M-tile x 4 N-tiles
  f32x4 acc2[4];
#pragma unroll
  for (int nt = 0; nt < 4; ++nt) acc2[nt] = {0.f, 0.f, 0.f, 0.f};
  for (int k = 0; k < 16; ++k) {
    short8 a = *(const short8*)(act + (wave * 16 + ccol) * 520 + k * 32 + ((lane >> 4) << 3));
#pragma unroll
    for (int nt = 0; nt < 4; ++nt) {
      short8 b = *(const short8*)(hs + (nt * 16 + ccol) * 520 + k * 32 + ((lane >> 4) << 3));
      acc2[nt] = __builtin_amdgcn_mfma_f32_16x16x32_bf16(a, b, acc2[nt], 0, 0, 0);
    }
  }
#pragma unroll
  for (int nt = 0; nt < 4; ++nt) {
    int o = nt * 16 + ccol;
    float bias = b2[o];
#pragma unroll
    for (int j = 0; j < 4; ++j) {
      int r = wave * 16 + crow + j;
      out[(row0 + r) * 64 + o] = acc2[nt][j] + bias;
    }
  }
}

extern "C" void kernel_launch(void* const* d_in, const int* in_sizes, int n_in,
                              void* d_out, int out_size, void* d_ws, size_t ws_size,
                              hipStream_t stream) {
  const float* x  = (const float*)d_in[0];
  const float* h0 = (const float*)d_in[1];
  const float* Wz = (const float*)d_in[2];
  const float* Wr = (const float*)d_in[3];
  const float* Wh = (const float*)d_in[4];
  const float* bz = (const float*)d_in[5];
  const float* br = (const float*)d_in[6];
  const float* bh = (const float*)d_in[7];
  const float* W1 = (const float*)d_in[8];
  const float* b1 = (const float*)d_in[9];
  const float* W2 = (const float*)d_in[10];
  const float* b2 = (const float*)d_in[11];

  char* ws = (char*)d_ws;
  size_t off = 0;
  unsigned int*   ctr   = (unsigned int*)(ws + off);   off += 32768;
  unsigned short* hbuf  = (unsigned short*)(ws + off); off += 32 * 512 * 2;
  unsigned short* rhbuf = (unsigned short*)(ws + off); off += 32 * 512 * 2;
  unsigned short* WgT   = (unsigned short*)(ws + off); off += (size_t)1536 * 576 * 2;
  unsigned short* W1T   = (unsigned short*)(ws + off); off += (size_t)512 * 512 * 2;
  unsigned short* W2T   = (unsigned short*)(ws + off); off += (size_t)64 * 512 * 2;
  unsigned short* h_all = (unsigned short*)(ws + off); off += (size_t)32 * 2048 * 512 * 2;

  float* out = (float*)d_out;
  float* h_last = out + (size_t)32 * 2048 * 64;

  hipMemsetAsync(ctr, 0, 32768, stream);
  hipLaunchKernelGGL(prep_kernel, dim3(1024), dim3(256), 0, stream,
                     Wz, Wr, Wh, W1, W2, WgT, W1T, W2T);

  const int recur_lds = (96 * KPAD + 16 * KPAD) * 2 + 16 * 32 * 4;
  hipFuncSetAttribute(reinterpret_cast<const void*>(&recur_kernel),
                      hipFuncAttributeMaxDynamicSharedMemorySize, recur_lds);
  hipLaunchKernelGGL(recur_kernel, dim3(32), dim3(256), recur_lds, stream,
                     x, h0, bz, br, bh, WgT, hbuf, rhbuf, h_all, h_last, ctr);

  const int head_lds = 2 * 64 * 520 * 2;
  hipFuncSetAttribute(reinterpret_cast<const void*>(&head_kernel),
                      hipFuncAttributeMaxDynamicSharedMemorySize, head_lds);
  hipLaunchKernelGGL(head_kernel, dim3(1024), dim3(256), head_lds, stream,
                     h_all, W1T, W2T, b1, b2, out);
}

// Round 2
// 17055.139 us; speedup vs baseline: 1.1339x; 1.1339x over previous
//
#include <hip/hip_runtime.h>
#include <stdint.h>

#define S_LEN 2048

typedef unsigned long long u64;
typedef __attribute__((ext_vector_type(8))) short short8;
typedef __attribute__((ext_vector_type(4))) float f32x4;

__device__ __forceinline__ unsigned short f2bf(float f) {
  union { float f; unsigned int u; } v; v.f = f;
  unsigned int u = v.u;
  u = (u + 0x7FFFu + ((u >> 16) & 1u)) >> 16;   // round-to-nearest-even
  return (unsigned short)u;
}

__device__ __forceinline__ void st_bf(unsigned short* p, unsigned short v) {
  __hip_atomic_store(p, v, __ATOMIC_RELAXED, __HIP_MEMORY_SCOPE_AGENT);
}
__device__ __forceinline__ u64 ld_u64(const unsigned short* p) {
  return __hip_atomic_load((const u64*)p, __ATOMIC_RELAXED, __HIP_MEMORY_SCOPE_AGENT);
}

// ---- prep: cast/reorder weights to bf16 in workspace --------------------
__global__ void prep_kernel(const float* __restrict__ Wz, const float* __restrict__ Wr,
                            const float* __restrict__ Wh, const float* __restrict__ W1,
                            const float* __restrict__ W2,
                            unsigned short* __restrict__ WgT,
                            unsigned short* __restrict__ W1T,
                            unsigned short* __restrict__ W2T) {
  const int total = 1536 * 576 + 512 * 512 + 64 * 512;
  for (int idx = blockIdx.x * 256 + threadIdx.x; idx < total; idx += gridDim.x * 256) {
    if (idx < 1536 * 576) {
      int row = idx / 576, k = idx % 576;
      float v;
      if (row < 512)       v = Wz[row * 576 + k];
      else if (row < 1024) v = Wr[(row - 512) * 576 + k];
      else {
        int r = row - 1024;
        v = (k < 64) ? Wh[r * 576 + 512 + k] : Wh[r * 576 + (k - 64)];
      }
      WgT[idx] = f2bf(v);
    } else if (idx < 1536 * 576 + 512 * 512) {
      int i = idx - 1536 * 576;
      W1T[i] = f2bf(W1[i]);
    } else {
      int i = idx - 1536 * 576 - 512 * 512;
      W2T[i] = f2bf(W2[i]);
    }
  }
}

// ---- recurrence: 32 WGs = 2 batch-groups x 16 column-slice WGs ----------
// Weights in fragment-contiguous LDS (lane l reads block + l*16B, stride-1).
// A-operand h/rh fragments loaded per-lane directly from hbuf/rhbuf with
// relaxed AGENT (sc1) loads -- no LDS staging, no L2 flush/invalidate.
// Sync: per-WG monotone flag (64B padded) + 16-lane spin, fresh value/phase.
__global__ void __launch_bounds__(256, 1) recur_kernel(
    const float* __restrict__ x, const float* __restrict__ h0,
    const float* __restrict__ bz, const float* __restrict__ br,
    const float* __restrict__ bh, const unsigned short* __restrict__ WgT,
    unsigned short* __restrict__ hbuf, unsigned short* __restrict__ rhbuf,
    unsigned short* __restrict__ h_all, float* __restrict__ h_last,
    unsigned int* __restrict__ flags) {
  extern __shared__ char smem[];
  unsigned short* Wf = (unsigned short*)smem;        // 6 tiles x 18 kk x 64 lanes x 8 bf16
  unsigned short* Xf = Wf + 6 * 18 * 64 * 8;         // 2 kk x 64 lanes x 8 bf16
  float* hfp = (float*)(Xf + 2 * 64 * 8);            // [16][32] fp32 state

  const int wg = blockIdx.x;
  const int g = wg >> 4, w = wg & 15;
  const int tid = threadIdx.x;
  const int lane = tid & 63, wave = tid >> 6;
  const int crow = (lane >> 4) << 2;   // C/D row base
  const int ccol = lane & 15;          // C/D col == A row
  const int ko8 = (lane >> 4) << 3;    // k sub-offset in shorts

  // ---- one-time: weight fragments into LDS (read order == lane order) ----
  for (int i = tid; i < 6 * 18 * 64; i += 256) {
    int T = i / (18 * 64);
    int kk = (i >> 6) % 18;
    int l = i & 63;
    int row = (T >> 1) * 512 + w * 32 + (T & 1) * 16 + (l & 15);
    int k = kk * 32 + ((l >> 4) << 3);
    uint4 v = *(const uint4*)(WgT + (size_t)row * 576 + k);
    *(uint4*)(Wf + (size_t)i * 8) = v;
  }
  // ---- h state: fp32 in LDS + publish bf16 h0 slice ----
  for (int i = tid; i < 512; i += 256) {
    int m = i >> 5, c = i & 31;
    float hv = h0[(size_t)(g * 16 + m) * 512 + w * 32 + c];
    hfp[m * 32 + c] = hv;
    st_bf(hbuf + (size_t)(g * 16 + m) * 512 + w * 32 + c, f2bf(hv));
  }
  // ---- x(0) into Xf fragments ----
  const int pm = tid >> 4, pf4 = tid & 15;
  float4 xreg = *(const float4*)(x + ((size_t)(g * 16 + pm) * S_LEN + 0) * 64 + pf4 * 4);
  {
    int c = pf4 >> 1;
    int F = (c >> 2) * 64 + (c & 3) * 16 + pm;
    unsigned short tmp[4] = {f2bf(xreg.x), f2bf(xreg.y), f2bf(xreg.z), f2bf(xreg.w)};
    *(u64*)(Xf + F * 8 + (pf4 & 1) * 4) = *(u64*)tmp;
  }
  __syncthreads();   // compiler drains vmcnt(0) before s_barrier -> publishes visible

  unsigned int* myflag = flags + g * 256 + w * 16;        // 64B-padded flags
  const unsigned int* gflags = flags + g * 256;
  if (tid == 0)
    __hip_atomic_store(myflag, 1u, __ATOMIC_RELAXED, __HIP_MEMORY_SCOPE_AGENT);

  float bzv = 0.f, brv = 0.f, bhv = 0.f;
  if (wave < 2) { bzv = bz[w * 32 + wave * 16 + ccol]; bhv = bh[w * 32 + wave * 16 + ccol]; }
  else          { brv = br[w * 32 + (wave & 1) * 16 + ccol]; }

  const unsigned short* hsrc  = hbuf  + (size_t)(g * 16 + ccol) * 512 + ko8;
  const unsigned short* rhsrc = rhbuf + (size_t)(g * 16 + ccol) * 512 + ko8;

  float zreg[4];

  for (int t = 0; t < S_LEN; ++t) {
    // ===== wait: h(t-1) published by all WGs =====
    if (wave == 0) {
      const unsigned int* fl = gflags + (lane & 15) * 16;
      unsigned int it = 0;
      for (;;) {
        unsigned int v = __hip_atomic_load(fl, __ATOMIC_RELAXED, __HIP_MEMORY_SCOPE_AGENT);
        if (__all((int)(v >= (unsigned)(2 * t + 1)))) break;
        if (++it > (1u << 22)) break;   // safety: never hang
      }
    }
    __syncthreads();

    // ===== phase A: z (waves 0,1) and r (waves 2,3), K = [x(64); h(512)] =====
    short8 aarr[16];
#pragma unroll
    for (int kk = 0; kk < 16; ++kk) {
      union { u64 q[2]; short8 v; } u;
      u.q[0] = ld_u64(hsrc + kk * 32);
      u.q[1] = ld_u64(hsrc + kk * 32 + 4);
      aarr[kk] = u.v;
    }
    const unsigned short* Bb = Wf + (size_t)wave * 18 * 512 + lane * 8;
    short8 ax0 = *(const short8*)(Xf + (0 * 64 + lane) * 8);
    short8 ax1 = *(const short8*)(Xf + (1 * 64 + lane) * 8);
    f32x4 acc0 = {0.f, 0.f, 0.f, 0.f}, acc1 = {0.f, 0.f, 0.f, 0.f};
    acc0 = __builtin_amdgcn_mfma_f32_16x16x32_bf16(ax0, *(const short8*)(Bb + 0 * 512), acc0, 0, 0, 0);
    acc1 = __builtin_amdgcn_mfma_f32_16x16x32_bf16(ax1, *(const short8*)(Bb + 1 * 512), acc1, 0, 0, 0);
#pragma unroll
    for (int kk = 0; kk < 16; kk += 2) {
      acc0 = __builtin_amdgcn_mfma_f32_16x16x32_bf16(aarr[kk],     *(const short8*)(Bb + (kk + 2) * 512), acc0, 0, 0, 0);
      acc1 = __builtin_amdgcn_mfma_f32_16x16x32_bf16(aarr[kk + 1], *(const short8*)(Bb + (kk + 3) * 512), acc1, 0, 0, 0);
    }
    f32x4 acc = acc0 + acc1;
    if (wave < 2) {
#pragma unroll
      for (int j = 0; j < 4; ++j)
        zreg[j] = 1.f / (1.f + __expf(-(acc[j] + bzv)));
    } else {
      const int nloc = (wave & 1) * 16 + ccol;
      const int ng = w * 32 + nloc;
#pragma unroll
      for (int j = 0; j < 4; ++j) {
        int m = crow + j;
        float rv = 1.f / (1.f + __expf(-(acc[j] + brv)));
        float rh = rv * hfp[m * 32 + nloc];
        st_bf(rhbuf + (size_t)(g * 16 + m) * 512 + ng, f2bf(rh));
      }
    }
    __syncthreads();   // drains rh publishes (per-wave vmcnt(0) before s_barrier)
    if (tid == 0)
      __hip_atomic_store(myflag, (unsigned)(2 * t + 2), __ATOMIC_RELAXED, __HIP_MEMORY_SCOPE_AGENT);

    // ===== wait: rh published by all WGs =====
    if (wave == 0) {
      const unsigned int* fl = gflags + (lane & 15) * 16;
      unsigned int it = 0;
      for (;;) {
        unsigned int v = __hip_atomic_load(fl, __ATOMIC_RELAXED, __HIP_MEMORY_SCOPE_AGENT);
        if (__all((int)(v >= (unsigned)(2 * t + 2)))) break;
        if (++it > (1u << 22)) break;
      }
    }
    __syncthreads();

    // prefetch x(t+1): latency hides under phase B, drained at its barrier
    int tn = (t + 1 < S_LEN) ? t + 1 : t;
    xreg = *(const float4*)(x + ((size_t)(g * 16 + pm) * S_LEN + tn) * 64 + pf4 * 4);

    // ===== phase B: h_hat + state update (waves 0,1), K = [x(64); rh(512)] =====
    if (wave < 2) {
      short8 barr[16];
#pragma unroll
      for (int kk = 0; kk < 16; ++kk) {
        union { u64 q[2]; short8 v; } u2;
        u2.q[0] = ld_u64(rhsrc + kk * 32);
        u2.q[1] = ld_u64(rhsrc + kk * 32 + 4);
        barr[kk] = u2.v;
      }
      const unsigned short* Bh = Wf + (size_t)(4 + wave) * 18 * 512 + lane * 8;
      f32x4 b0 = {0.f, 0.f, 0.f, 0.f}, b1 = {0.f, 0.f, 0.f, 0.f};
      b0 = __builtin_amdgcn_mfma_f32_16x16x32_bf16(ax0, *(const short8*)(Bh + 0 * 512), b0, 0, 0, 0);
      b1 = __builtin_amdgcn_mfma_f32_16x16x32_bf16(ax1, *(const short8*)(Bh + 1 * 512), b1, 0, 0, 0);
#pragma unroll
      for (int kk = 0; kk < 16; kk += 2) {
        b0 = __builtin_amdgcn_mfma_f32_16x16x32_bf16(barr[kk],     *(const short8*)(Bh + (kk + 2) * 512), b0, 0, 0, 0);
        b1 = __builtin_amdgcn_mfma_f32_16x16x32_bf16(barr[kk + 1], *(const short8*)(Bh + (kk + 3) * 512), b1, 0, 0, 0);
      }
      f32x4 hacc = b0 + b1;
      const int nloc = wave * 16 + ccol;
      const int ng = w * 32 + nloc;
#pragma unroll
      for (int j = 0; j < 4; ++j) {
        int m = crow + j;
        float e = __expf(2.f * (hacc[j] + bhv));
        float hh = 1.f - 2.f / (e + 1.f);
        float hold = hfp[m * 32 + nloc];
        float z = zreg[j];
        float hn = (1.f - z) * hold + z * hh;
        hfp[m * 32 + nloc] = hn;
        unsigned short hb = f2bf(hn);
        st_bf(hbuf + (size_t)(g * 16 + m) * 512 + ng, hb);
        h_all[((size_t)(g * 16 + m) * S_LEN + t) * 512 + ng] = hb;
        if (t == S_LEN - 1) h_last[(size_t)(g * 16 + m) * 512 + ng] = hn;
      }
    }
    __syncthreads();   // drains h publishes
    if (tid == 0)
      __hip_atomic_store(myflag, (unsigned)(2 * t + 3), __ATOMIC_RELAXED, __HIP_MEMORY_SCOPE_AGENT);

    // stage x(t+1) fragments (own-WG use only; next top syncthreads orders it)
    {
      int c = pf4 >> 1;
      int F = (c >> 2) * 64 + (c & 3) * 16 + pm;
      unsigned short tmp[4] = {f2bf(xreg.x), f2bf(xreg.y), f2bf(xreg.z), f2bf(xreg.w)};
      *(u64*)(Xf + F * 8 + (pf4 & 1) * 4) = *(u64*)tmp;
    }
  }
}

// ---- head: out = relu(h_all @ W1^T + b1) @ W2^T + b2 --------------------
__global__ void __launch_bounds__(256, 1) head_kernel(
    const unsigned short* __restrict__ h_all, const unsigned short* __restrict__ W1T,
    const unsigned short* __restrict__ W2T, const float* __restrict__ b1,
    const float* __restrict__ b2, float* __restrict__ out) {
  extern __shared__ char smem[];
  unsigned short* hs = (unsigned short*)smem;   // [64][520]
  unsigned short* act = hs + 64 * 520;          // [64][520]

  const int tid = threadIdx.x, lane = tid & 63, wave = tid >> 6;
  const int crow = (lane >> 4) << 2, ccol = lane & 15;
  const size_t row0 = (size_t)blockIdx.x * 64;

  for (int i = tid; i < 64 * 64; i += 256) {
    int r = i >> 6, c8 = i & 63;
    uint4 v = *(const uint4*)(h_all + (row0 + r) * 512 + c8 * 8);
    *(uint4*)(hs + r * 520 + c8 * 8) = v;
  }
  __syncthreads();

  f32x4 acc[8][4];
#pragma unroll
  for (int nt = 0; nt < 8; ++nt)
#pragma unroll
    for (int mt = 0; mt < 4; ++mt) acc[nt][mt] = {0.f, 0.f, 0.f, 0.f};

  for (int k = 0; k < 16; ++k) {
    short8 a[4];
#pragma unroll
    for (int mt = 0; mt < 4; ++mt)
      a[mt] = *(const short8*)(hs + (mt * 16 + ccol) * 520 + k * 32 + ((lane >> 4) << 3));
#pragma unroll
    for (int nt = 0; nt < 8; ++nt) {
      int n0 = (wave * 8 + nt) * 16;
      short8 b = *(const short8*)(W1T + (size_t)(n0 + ccol) * 512 + k * 32 + ((lane >> 4) << 3));
#pragma unroll
      for (int mt = 0; mt < 4; ++mt)
        acc[nt][mt] = __builtin_amdgcn_mfma_f32_16x16x32_bf16(a[mt], b, acc[nt][mt], 0, 0, 0);
    }
  }
#pragma unroll
  for (int nt = 0; nt < 8; ++nt) {
    int n = wave * 128 + nt * 16 + ccol;
    float bias = b1[n];
#pragma unroll
    for (int mt = 0; mt < 4; ++mt)
#pragma unroll
      for (int j = 0; j < 4; ++j) {
        float v = fmaxf(acc[nt][mt][j] + bias, 0.f);
        act[(mt * 16 + crow + j) * 520 + n] = f2bf(v);
      }
  }
  __syncthreads();
  for (int i = tid; i < 64 * 64; i += 256) {
    int r = i >> 6, c8 = i & 63;
    uint4 v = *(const uint4*)(W2T + (size_t)r * 512 + c8 * 8);
    *(uint4*)(hs + r * 520 + c8 * 8) = v;
  }
  __syncthreads();

  f32x4 acc2[4];
#pragma unroll
  for (int nt = 0; nt < 4; ++nt) acc2[nt] = {0.f, 0.f, 0.f, 0.f};
  for (int k = 0; k < 16; ++k) {
    short8 a = *(const short8*)(act + (wave * 16 + ccol) * 520 + k * 32 + ((lane >> 4) << 3));
#pragma unroll
    for (int nt = 0; nt < 4; ++nt) {
      short8 b = *(const short8*)(hs + (nt * 16 + ccol) * 520 + k * 32 + ((lane >> 4) << 3));
      acc2[nt] = __builtin_amdgcn_mfma_f32_16x16x32_bf16(a, b, acc2[nt], 0, 0, 0);
    }
  }
#pragma unroll
  for (int nt = 0; nt < 4; ++nt) {
    int o = nt * 16 + ccol;
    float bias = b2[o];
#pragma unroll
    for (int j = 0; j < 4; ++j) {
      int r = wave * 16 + crow + j;
      out[(row0 + r) * 64 + o] = acc2[nt][j] + bias;
    }
  }
}

extern "C" void kernel_launch(void* const* d_in, const int* in_sizes, int n_in,
                              void* d_out, int out_size, void* d_ws, size_t ws_size,
                              hipStream_t stream) {
  const float* x  = (const float*)d_in[0];
  const float* h0 = (const float*)d_in[1];
  const float* Wz = (const float*)d_in[2];
  const float* Wr = (const float*)d_in[3];
  const float* Wh = (const float*)d_in[4];
  const float* bz = (const float*)d_in[5];
  const float* br = (const float*)d_in[6];
  const float* bh = (const float*)d_in[7];
  const float* W1 = (const float*)d_in[8];
  const float* b1 = (const float*)d_in[9];
  const float* W2 = (const float*)d_in[10];
  const float* b2 = (const float*)d_in[11];

  char* ws = (char*)d_ws;
  size_t off = 0;
  unsigned int*   flags = (unsigned int*)(ws + off);   off += 4096;
  unsigned short* hbuf  = (unsigned short*)(ws + off); off += 32 * 512 * 2;
  unsigned short* rhbuf = (unsigned short*)(ws + off); off += 32 * 512 * 2;
  unsigned short* WgT   = (unsigned short*)(ws + off); off += (size_t)1536 * 576 * 2;
  unsigned short* W1T   = (unsigned short*)(ws + off); off += (size_t)512 * 512 * 2;
  unsigned short* W2T   = (unsigned short*)(ws + off); off += (size_t)64 * 512 * 2;
  unsigned short* h_all = (unsigned short*)(ws + off); off += (size_t)32 * 2048 * 512 * 2;

  float* out = (float*)d_out;
  float* h_last = out + (size_t)32 * 2048 * 64;

  hipMemsetAsync(flags, 0, 4096, stream);
  hipLaunchKernelGGL(prep_kernel, dim3(1024), dim3(256), 0, stream,
                     Wz, Wr, Wh, W1, W2, WgT, W1T, W2T);

  const int recur_lds = (6 * 18 * 64 * 8 + 2 * 64 * 8) * 2 + 16 * 32 * 4;
  hipFuncSetAttribute(reinterpret_cast<const void*>(&recur_kernel),
                      hipFuncAttributeMaxDynamicSharedMemorySize, recur_lds);
  hipLaunchKernelGGL(recur_kernel, dim3(32), dim3(256), recur_lds, stream,
                     x, h0, bz, br, bh, WgT, hbuf, rhbuf, h_all, h_last, flags);

  const int head_lds = 2 * 64 * 520 * 2;
  hipFuncSetAttribute(reinterpret_cast<const void*>(&head_kernel),
                      hipFuncAttributeMaxDynamicSharedMemorySize, head_lds);
  hipLaunchKernelGGL(head_kernel, dim3(1024), dim3(256), head_lds, stream,
                     h_all, W1T, W2T, b1, b2, out);
}